// Round 6
// baseline (203.855 us; speedup 1.0000x reference)
//
#include <hip/hip_runtime.h>
#include <hip/hip_bf16.h>
#include <math.h>

#define H 24
#define IN 8
#define THREADS 384            // 6 waves; 384 % 6 == 0 keeps q fixed per thread
#define ITERS 6                // columns per block = THREADS*ITERS/6 = 384

// cst layout in d_ws (floats):
//   [0..191]   Pz[24][8] = softplus(e_p)*softplus(P)
//   [192..383] Pw[24][8] = P (raw)
//   [384..407] Az[24]    = softplus(e)*(softplus(W)@r) + b_z
//   [408..431] Av[24]    = (W@(U*X*r)) + b_v
//   [432..455] V0[24]    = v0
// float4 view: Pz f4[0..47], Pw f4[48..95], Az f4[96..101], Av f4[102..107], V0 f4[108..113]

__device__ __forceinline__ float sigm(float v) {
    return 1.0f / (1.0f + __expf(-v));
}
__device__ __forceinline__ float softplus_f(float v) {
    return fmaxf(v, 0.0f) + log1pf(__expf(-fabsf(v)));
}

__global__ __launch_bounds__(256) void precompute_kernel(
        const float* __restrict__ W, const float* __restrict__ P,
        const float* __restrict__ b_v, const float* __restrict__ b_z,
        const float* __restrict__ e, const float* __restrict__ e_p,
        const float* __restrict__ c_x, const float* __restrict__ c_u,
        const float* __restrict__ c_U, const float* __restrict__ v0,
        const float* __restrict__ X0, const float* __restrict__ U0,
        float* __restrict__ cst) {
    __shared__ float rr[H];
    __shared__ float mm[H];
    const int t = threadIdx.x;

    if (t < H) {
        const float r = sigm(v0[t]);
        rr[t] = r;
        const float zx   = 0.001f + 0.099f * sigm(c_x[t]);
        const float Xs   = zx + (1.0f - zx) * X0[t] - U0[t] * X0[t] * r;
        const float zu   = 0.001f + 0.099f * sigm(c_u[t]);
        const float Ucap = 0.9f * sigm(c_U[t]);
        float U = Ucap * zu + (1.0f - zu) * U0[t] + Ucap * (1.0f - U0[t]) * r;
        U = fminf(fmaxf(U, Ucap), 1.0f);
        mm[t] = U * Xs * r;
    }
    __syncthreads();
    if (t < H) {
        const float spe = softplus_f(e[0]);
        float kr = 0.0f, wc = 0.0f;
        #pragma unroll
        for (int j = 0; j < H; ++j) {
            const float w = W[t * H + j];
            kr = fmaf(softplus_f(w), rr[j], kr);
            wc = fmaf(w, mm[j], wc);
        }
        cst[384 + t] = fmaf(spe, kr, b_z[t]);
        cst[408 + t] = wc + b_v[t];
        cst[432 + t] = v0[t];
    }
    for (int k = t; k < H * IN; k += blockDim.x) {
        const float p = P[k];
        cst[k]       = softplus_f(e_p[0]) * softplus_f(p);
        cst[192 + k] = p;
    }
}

// compile-time float4 component extract (idx must be an unrolled-loop constant)
#define COMP(v, j) ((j) == 0 ? (v).x : (j) == 1 ? (v).y : (j) == 2 ? (v).z : (v).w)

__global__ __launch_bounds__(THREADS) void cbrnn_main_kernel(
        const float* __restrict__ x,    // (IN, B)
        const float* __restrict__ cst,  // 456 floats (L1/L2-resident)
        float* __restrict__ out,        // (B, H) row-major
        int B) {
    const int tid = threadIdx.x;
    const int q   = tid % 6;            // h-quad owned by this lane (fixed)
    const int cb  = tid / 6;            // 0..63: column within iteration slice

    // ---- per-thread constants for quad q: 11 float4, loaded once (L1-hot)
    const float4* cf = (const float4*)cst;
    float4 pz[4][2], pw[4][2];
    #pragma unroll
    for (int hh = 0; hh < 4; ++hh) {
        pz[hh][0] = cf[(4 * q + hh) * 2 + 0];
        pz[hh][1] = cf[(4 * q + hh) * 2 + 1];
        pw[hh][0] = cf[48 + (4 * q + hh) * 2 + 0];
        pw[hh][1] = cf[48 + (4 * q + hh) * 2 + 1];
    }
    const float4 az  = cf[96 + q];
    const float4 av  = cf[102 + q];
    const float4 v0q = cf[108 + q];

    const long colbase  = (long)blockIdx.x * (THREADS / 6 * ITERS) + cb;
    const long slotbase = (long)blockIdx.x * (THREADS * ITERS) + tid;
    float4* out4 = (float4*)out;

    #pragma unroll
    for (int it = 0; it < ITERS; ++it) {
        const long col = colbase + (long)(THREADS / 6) * it;
        if (col < (long)B) {
            // x column: 8 scalar loads; 6 adjacent lanes share each address (L1 broadcast)
            float xv[IN];
            #pragma unroll
            for (int i = 0; i < IN; ++i) xv[i] = x[(long)i * B + col];

            float res[4];
            #pragma unroll
            for (int hh = 0; hh < 4; ++hh) {
                float sz = COMP(az, hh);
                float sv = COMP(av, hh);
                #pragma unroll
                for (int i = 0; i < 4; ++i) {
                    sz = fmaf(COMP(pz[hh][0], i), xv[i], sz);
                    sv = fmaf(COMP(pw[hh][0], i), xv[i], sv);
                    sz = fmaf(COMP(pz[hh][1], i), xv[4 + i], sz);
                    sv = fmaf(COMP(pw[hh][1], i), xv[4 + i], sv);
                }
                const float V0h = COMP(v0q, hh);
                res[hh] = fmaf(0.1f, fmaf(-sigm(sz), V0h, sv), V0h);
            }
            // store: addr = base + 16*tid -> consecutive lanes, consecutive 16B (dense)
            float4 r4 = {res[0], res[1], res[2], res[3]};
            out4[slotbase + (long)THREADS * it] = r4;
        }
    }
}

extern "C" void kernel_launch(void* const* d_in, const int* in_sizes, int n_in,
                              void* d_out, int out_size, void* d_ws, size_t ws_size,
                              hipStream_t stream) {
    const float* x   = (const float*)d_in[0];
    const float* W   = (const float*)d_in[1];
    const float* P   = (const float*)d_in[2];
    const float* b_v = (const float*)d_in[3];
    const float* b_z = (const float*)d_in[4];
    const float* e   = (const float*)d_in[5];
    const float* e_p = (const float*)d_in[6];
    const float* c_x = (const float*)d_in[7];
    const float* c_u = (const float*)d_in[8];
    const float* c_U = (const float*)d_in[9];
    const float* v0  = (const float*)d_in[10];
    const float* X0  = (const float*)d_in[11];
    const float* U0  = (const float*)d_in[12];
    float* out = (float*)d_out;
    float* cst = (float*)d_ws;

    const int B = in_sizes[0] / IN;

    precompute_kernel<<<1, 256, 0, stream>>>(W, P, b_v, b_z, e, e_p,
                                             c_x, c_u, c_U, v0, X0, U0, cst);
    const int cols_per_block = THREADS / 6 * ITERS;   // 384
    const int grid = (B + cols_per_block - 1) / cols_per_block;
    cbrnn_main_kernel<<<grid, THREADS, 0, stream>>>(x, cst, out, B);
}